// Round 13
// baseline (25.063 us; speedup 1.0000x reference)
//
#include <hip/hip_runtime.h>
#include <math.h>

// Voxelized chamfer via bf16 MFMA (32x32x16 core), SINGLE dispatch.
//   vox coords are integer-valued fp32, |v| <= ~160 -> EXACT in bf16.
//   A row i : {-2qx, -2qy, -2qz, 1, 1, 0...}   (-2q = exponent shift, exact)
//   B col j : { cx,   cy,   cz, yh, yl, 0...}  (yy = yh+yl exact bf16 split)
//   MFMA   -> yy_j - 2 q_i.c_j  directly; 16-term fp32 accum of exact ints
//   < 2^20 -> exact. row-min + xx_i = chamfer row-min; 1 min3 / 2 evals.
//   loss = mean(row-mins, pred->gt) + mean(row-mins, gt->pred).
//
// 512 blocks = (dir, batch, 64-query tile). Stage all 4096 candidates as
// packed 16B B-frags in LDS (float4 loads; ALL IEEE divides here, bit-
// identical to reference). Each of 4 waves scans 32 col-tiles of 32 in
// pairs: 2 ds_read_b128 + 4 MFMA_32x32x16 + 32 min3. Row-min wrap-up:
// 5-level shfl min, +xx, cross-wave LDS min, exact int sum = partial.
//
// FENCE-FREE fused finish (R10's __threadfence L2-writeback was the cost):
//   1. atomicExch(&partials[bid], v)   — device-scope RMW at the coherent
//      point; no cache flush needed for visibility.
//   2. s_waitcnt vmcnt(0)              — orders (1) before (2) in HW.
//   3. old = atomicAdd(ticket, 1)      — (old & 511)==511 marks the LAST
//      block of THIS call for ANY initial counter value: 512 consecutive
//      tickets hit every residue exactly once -> poison-safe, no reset.
//   4. Last block only: read the 512 partials via atomicAdd(p, 0.0f)
//      (coherent reads, 2 per thread), fixed-order LDS tree sum,
//      out[0] = sum * 2^-14. Exactly one writer -> deterministic; partials
//      are always written (step 1) before any read (proven by the count).
//
// Exactness: all staged values integer & bf16-exact (|v|<=512 even / <=2^17
// with <=9 sig bits); MFMA products <= ~2^17, 5-term fp32 accum exact; row
// mins exact ints; per-block partial = sum of 64 ints < 2^25 exact; final
// fixed-order tree of 512 exact ints; SCALE = 2^-14 exact.

typedef float  f32x16 __attribute__((ext_vector_type(16)));
typedef short  bf16x8 __attribute__((ext_vector_type(8)));

constexpr int NPTS  = 4096;
constexpr int BLK   = 256;
constexpr int QPB   = 64;             // query rows per block (2 tiles of 32)
constexpr int NTB   = NPTS / QPB;     // 64 row tiles per (dir, batch)
constexpr int BATCH = 4;
constexpr int NBLOCKS = 2 * BATCH * NTB;   // 512
constexpr float FINF  = 3.402823466e38f;
constexpr float SCALE = 1.0f / 16384.0f;   // 1/(B*N) = 2^-14, exact

__device__ __forceinline__ float vox(float c, float off) {
    return truncf((c + off) / 0.05f);  // IEEE div: bit-matches reference
}
__device__ __forceinline__ unsigned bfbits(float v) {
    return __float_as_uint(v) >> 16;   // exact for the value classes used
}
__device__ __forceinline__ float min3f(float a, float b, float c) {
    return fminf(fminf(a, b), c);      // clang fuses to v_min3_f32
}
__device__ __forceinline__ int4 packB(float x, float y, float z) {
    const float yy = fmaf(z, z, fmaf(y, y, x * x));      // exact int
    const float hi = floorf(yy * 0.00390625f) * 256.0f;  // exact
    const float lo = yy - hi;                            // in [0,256)
    return make_int4(
        (int)((bfbits(y) << 16) | bfbits(x)),            // k0:cx k1:cy
        (int)((bfbits(hi) << 16) | bfbits(z)),           // k2:cz k3:yh
        (int)(bfbits(lo)),                               // k4:yl k5:0
        0);
}

__global__ __launch_bounds__(BLK) void chamfer_fused_kernel(
    const float* __restrict__ preds,
    const float* __restrict__ gts,
    float* __restrict__ partials,      // [512]
    unsigned* __restrict__ ticket,     // persistent; any base value works
    float* __restrict__ out)
{
    __shared__ int4  cfrag[NPTS];      // candidate B-frags (64 KB)
    __shared__ int4  qfrag[QPB];       // query A-frags (prescaled -2, ones)
    __shared__ float qxx[QPB];         // query squared norms (exact ints)
    __shared__ float waveRow[4][QPB];
    __shared__ float s1[BLK];
    __shared__ int   lastFlag;

    const int t    = threadIdx.x;
    const int bid  = blockIdx.x;        // dir*256 + b*64 + tile
    const int dir  = bid >> 8;
    const int rem  = bid & 255;
    const int b    = rem >> 6;
    const int tile = rem & 63;
    const int w    = t >> 6;
    const int lane = t & 63;

    const float* __restrict__ xb = (dir ? gts : preds) + (size_t)b * NPTS * 3;
    const float* __restrict__ yb = (dir ? preds : gts) + (size_t)b * NPTS * 3;

    constexpr unsigned ONE = 0x3F80u;   // bf16 1.0

    // ---- stage candidates: 4 points / thread / iter via 3 float4 loads ----
    const float4* __restrict__ yb4 = (const float4*)yb;
    #pragma unroll
    for (int it = 0; it < 4; ++it) {
        const int p0 = it * 1024 + t * 4;
        const int fi = it * 768  + t * 3;
        const float4 r0 = yb4[fi + 0];
        const float4 r1 = yb4[fi + 1];
        const float4 r2 = yb4[fi + 2];
        cfrag[p0+0] = packB(vox(r0.x,3.f), vox(r0.y,3.f), vox(r0.z,1.f));
        cfrag[p0+1] = packB(vox(r0.w,3.f), vox(r1.x,3.f), vox(r1.y,1.f));
        cfrag[p0+2] = packB(vox(r1.z,3.f), vox(r1.w,3.f), vox(r2.x,1.f));
        cfrag[p0+3] = packB(vox(r2.y,3.f), vox(r2.z,3.f), vox(r2.w,1.f));
    }
    // ---- stage this block's 64 query rows as A-frags ----
    if (t < QPB) {
        const int qi = tile * QPB + t;
        const float x = vox(xb[qi*3+0], 3.0f);
        const float y = vox(xb[qi*3+1], 3.0f);
        const float z = vox(xb[qi*3+2], 1.0f);
        qxx[t] = fmaf(z, z, fmaf(y, y, x * x));
        const float mx = -2.0f * x, my = -2.0f * y, mz = -2.0f * z; // exact
        qfrag[t] = make_int4(
            (int)((bfbits(my) << 16) | bfbits(mx)),          // k0 k1
            (int)((ONE << 16) | bfbits(mz)),                 // k2 k3:1
            (int)(ONE),                                      // k4:1 k5:0
            0);
    }
    __syncthreads();

    const int col  = lane & 31;         // A row / B col within 32-tile
    const bool lo_g = (lane < 32);      // k=0..7 carrier half

    // A fragments for the two 32-row query tiles (lanes>=32 zeroed -> B's
    // k8..15 contribute exactly 0).
    bf16x8 afrag[2];
    #pragma unroll
    for (int rt = 0; rt < 2; ++rt) {
        const int4 qv = qfrag[rt * 32 + col];
        int4 ai = { lo_g ? qv.x : 0, lo_g ? qv.y : 0, lo_g ? qv.z : 0, 0 };
        afrag[rt] = __builtin_bit_cast(bf16x8, ai);
    }

    f32x16 rm[2];
    #pragma unroll
    for (int rt = 0; rt < 2; ++rt)
        #pragma unroll
        for (int i = 0; i < 16; ++i) rm[rt][i] = FINF;
    const f32x16 zero = {};

    // ---- main loop: 32 col-tiles per wave, in pairs ----
    const int4* __restrict__ bbase = &cfrag[w * 1024 + col];
    #pragma unroll 4
    for (int jp = 0; jp < 16; ++jp) {
        const bf16x8 bfa = __builtin_bit_cast(bf16x8, bbase[jp * 64]);
        const bf16x8 bfb = __builtin_bit_cast(bf16x8, bbase[jp * 64 + 32]);

        const f32x16 dA0 = __builtin_amdgcn_mfma_f32_32x32x16_bf16(
            afrag[0], bfa, zero, 0, 0, 0);
        const f32x16 dB0 = __builtin_amdgcn_mfma_f32_32x32x16_bf16(
            afrag[0], bfb, zero, 0, 0, 0);
        const f32x16 dA1 = __builtin_amdgcn_mfma_f32_32x32x16_bf16(
            afrag[1], bfa, zero, 0, 0, 0);
        const f32x16 dB1 = __builtin_amdgcn_mfma_f32_32x32x16_bf16(
            afrag[1], bfb, zero, 0, 0, 0);

        #pragma unroll
        for (int i = 0; i < 16; ++i) {
            rm[0][i] = min3f(rm[0][i], dA0[i], dB0[i]);
            rm[1][i] = min3f(rm[1][i], dA1[i], dB1[i]);
        }
    }

    // ---- row-min wrap-up: min over 32 cols (5-level shfl in halves) ----
    const int hi4 = (lane >> 5) * 4;
    #pragma unroll
    for (int rt = 0; rt < 2; ++rt) {
        #pragma unroll
        for (int i = 0; i < 16; ++i) {
            float v = rm[rt][i];
            v = fminf(v, __shfl_xor(v, 1, 64));
            v = fminf(v, __shfl_xor(v, 2, 64));
            v = fminf(v, __shfl_xor(v, 4, 64));
            v = fminf(v, __shfl_xor(v, 8, 64));
            v = fminf(v, __shfl_xor(v, 16, 64));
            const int r = rt * 32 + (i & 3) + 8 * (i >> 2) + hi4; // m74/m101
            if (col == 0) waveRow[w][r] = v + qxx[r];
        }
    }
    __syncthreads();

    // ---- publish partial + fence-free last-block detection ----
    if (w == 0) {
        float v = fminf(fminf(waveRow[0][lane], waveRow[1][lane]),
                        fminf(waveRow[2][lane], waveRow[3][lane]));
        #pragma unroll
        for (int o = 32; o >= 1; o >>= 1) v += __shfl_xor(v, o, 64);
        if (lane == 0) {
            atomicExch(&partials[bid], v);     // coherent-point publish
            asm volatile("s_waitcnt vmcnt(0)" ::: "memory");  // order 1->2
            const unsigned old = atomicAdd(ticket, 1u);
            lastFlag = ((old & (NBLOCKS - 1)) == (NBLOCKS - 1)) ? 1 : 0;
        }
    }
    __syncthreads();

    // ---- fused finish: exactly one block per call reduces ----
    if (lastFlag) {
        const float a = atomicAdd(&partials[t], 0.0f);        // coherent read
        const float c = atomicAdd(&partials[t + 256], 0.0f);
        s1[t] = a + c;                                        // fixed order
        __syncthreads();
        for (int k = 128; k > 0; k >>= 1) {
            if (t < k) s1[t] += s1[t + k];
            __syncthreads();
        }
        if (t == 0) out[0] = s1[0] * SCALE;                   // exact
    }
}

extern "C" void kernel_launch(void* const* d_in, const int* in_sizes, int n_in,
                              void* d_out, int out_size, void* d_ws, size_t ws_size,
                              hipStream_t stream)
{
    const float* preds = (const float*)d_in[0];
    const float* gts   = (const float*)d_in[1];
    float* out = (float*)d_out;

    float*    partials = (float*)d_ws;                    // 512 floats
    unsigned* ticket   = (unsigned*)(partials + NBLOCKS); // persistent u32

    chamfer_fused_kernel<<<NBLOCKS, BLK, 0, stream>>>(
        preds, gts, partials, ticket, out);
}

// Round 15
// 21.538 us; speedup vs baseline: 1.1637x; 1.1637x over previous
//
#include <hip/hip_runtime.h>
#include <math.h>

// Voxelized chamfer via bf16 MFMA (32x32x16), occupancy-optimized:
//   vox coords are integer-valued fp32, |v| <= ~160 -> EXACT in bf16.
//   A row i : {-2qx, -2qy, -2qz, 1, 1, 0...}   (-2q = exponent shift, exact)
//   B col j : { cx,   cy,   cz, yh, yl, 0...}  (yy = yh+yl exact bf16 split)
//   MFMA   -> yy_j - 2 q_i.c_j  directly; 16-term fp32 accum of exact ints
//   < 2^20 -> exact. row-min + xx_i = chamfer row-min; 1 min3 / 2 evals.
//   loss = mean(row-mins, pred->gt) + mean(row-mins, gt->pred).
//
// [RESUBMIT of R14 — container died before compile/run; no signal obtained.]
//
// R11 diagnostic: scan is latency-bound at 2 blocks/CU (20% occupancy,
// 7.6 us measured vs ~1 us ideal). R13: fusion doesn't pay; 2 dispatches is
// the cheapest structure. This round: QPB=32 -> 1024 blocks = 4 blocks/CU
// resident (16 waves/CU, 2x latency hiding), candidate staging chunked
// 4 x 1024 points (16 KB LDS -> LDS never caps residency; barriers overlap
// across the 4 resident blocks). Scan math identical to R12's verified core.
//
// k1: 1024 blocks = (dir, batch, 32-query tile). Per chunk: pack 1024
//     candidates as 16B B-frags in LDS (float4 loads; ALL IEEE divides
//     here, bit-identical to reference), barrier, each of 4 waves scans
//     8 col-tiles of 32 in pairs: 2 ds_read_b128 + 2 MFMA_32x32x16 +
//     16 min3. Row-min wrap-up: 5-level shfl min (within 32-lane halves),
//     +xx, cross-wave LDS min, exact int sum -> partials[bid].
// k2: 1 block, fixed-order tree sum of 1024 partials, out[0] = sum * 2^-14.
//
// Exactness: all staged values integer & bf16-exact (|v|<=512 even / <=2^17
// with <=9 sig bits); MFMA products <= ~2^17, 5-term fp32 accum exact; row
// mins exact ints; per-block partial = sum of 32 ints < 2^24 exact; final
// fixed-order tree of 1024 exact ints; SCALE = 2^-14 exact.

typedef float  f32x16 __attribute__((ext_vector_type(16)));
typedef short  bf16x8 __attribute__((ext_vector_type(8)));

constexpr int NPTS   = 4096;
constexpr int BLK    = 256;
constexpr int QPB    = 32;             // query rows per block (one 32-tile)
constexpr int NTB    = NPTS / QPB;     // 128 row tiles per (dir, batch)
constexpr int BATCH  = 4;
constexpr int NBLOCKS = 2 * BATCH * NTB;   // 1024
constexpr int CHUNK  = 1024;           // candidates staged per chunk
constexpr float FINF  = 3.402823466e38f;
constexpr float SCALE = 1.0f / 16384.0f;   // 1/(B*N) = 2^-14, exact

__device__ __forceinline__ float vox(float c, float off) {
    return truncf((c + off) / 0.05f);  // IEEE div: bit-matches reference
}
__device__ __forceinline__ unsigned bfbits(float v) {
    return __float_as_uint(v) >> 16;   // exact for the value classes used
}
__device__ __forceinline__ float min3f(float a, float b, float c) {
    return fminf(fminf(a, b), c);      // clang fuses to v_min3_f32
}
__device__ __forceinline__ int4 packB(float x, float y, float z) {
    const float yy = fmaf(z, z, fmaf(y, y, x * x));      // exact int
    const float hi = floorf(yy * 0.00390625f) * 256.0f;  // exact
    const float lo = yy - hi;                            // in [0,256)
    return make_int4(
        (int)((bfbits(y) << 16) | bfbits(x)),            // k0:cx k1:cy
        (int)((bfbits(hi) << 16) | bfbits(z)),           // k2:cz k3:yh
        (int)(bfbits(lo)),                               // k4:yl k5:0
        0);
}

__global__ __launch_bounds__(BLK, 4) void chamfer_rows_kernel(
    const float* __restrict__ preds,
    const float* __restrict__ gts,
    float* __restrict__ partials)      // [1024]
{
    __shared__ int4  cfrag[CHUNK];     // candidate B-frags (16 KB)
    __shared__ int4  qfrag[QPB];       // query A-frags (prescaled -2, ones)
    __shared__ float qxx[QPB];         // query squared norms (exact ints)
    __shared__ float waveRow[4][QPB];

    const int t    = threadIdx.x;
    const int bid  = blockIdx.x;        // dir*512 + b*128 + tile
    const int dir  = bid >> 9;
    const int rem  = bid & 511;
    const int b    = rem >> 7;
    const int tile = rem & 127;
    const int w    = t >> 6;
    const int lane = t & 63;
    const int col  = lane & 31;         // A row / B col within 32-tile
    const bool lo_g = (lane < 32);      // k=0..7 carrier half

    const float* __restrict__ xb = (dir ? gts : preds) + (size_t)b * NPTS * 3;
    const float* __restrict__ yb = (dir ? preds : gts) + (size_t)b * NPTS * 3;

    constexpr unsigned ONE = 0x3F80u;   // bf16 1.0

    // ---- stage this block's 32 query rows as A-frags ----
    if (t < QPB) {
        const int qi = tile * QPB + t;
        const float x = vox(xb[qi*3+0], 3.0f);
        const float y = vox(xb[qi*3+1], 3.0f);
        const float z = vox(xb[qi*3+2], 1.0f);
        qxx[t] = fmaf(z, z, fmaf(y, y, x * x));
        const float mx = -2.0f * x, my = -2.0f * y, mz = -2.0f * z; // exact
        qfrag[t] = make_int4(
            (int)((bfbits(my) << 16) | bfbits(mx)),          // k0 k1
            (int)((ONE << 16) | bfbits(mz)),                 // k2 k3:1
            (int)(ONE),                                      // k4:1 k5:0
            0);
    }
    __syncthreads();

    // A fragment (lanes>=32 zeroed -> B's k8..15 contribute exactly 0).
    bf16x8 afrag;
    {
        const int4 qv = qfrag[col];
        int4 ai = { lo_g ? qv.x : 0, lo_g ? qv.y : 0, lo_g ? qv.z : 0, 0 };
        afrag = __builtin_bit_cast(bf16x8, ai);
    }

    f32x16 rm;
    #pragma unroll
    for (int i = 0; i < 16; ++i) rm[i] = FINF;
    const f32x16 zero = {};

    const float4* __restrict__ yb4 = (const float4*)yb;

    // ---- 4 chunks: pack 1024 candidates, barrier, scan ----
    #pragma unroll 1
    for (int cc = 0; cc < 4; ++cc) {
        if (cc) __syncthreads();           // previous chunk's readers done
        {
            const int p0 = t * 4;
            const int fi = cc * 768 + t * 3;
            const float4 r0 = yb4[fi + 0];
            const float4 r1 = yb4[fi + 1];
            const float4 r2 = yb4[fi + 2];
            cfrag[p0+0] = packB(vox(r0.x,3.f), vox(r0.y,3.f), vox(r0.z,1.f));
            cfrag[p0+1] = packB(vox(r0.w,3.f), vox(r1.x,3.f), vox(r1.y,1.f));
            cfrag[p0+2] = packB(vox(r1.z,3.f), vox(r1.w,3.f), vox(r2.x,1.f));
            cfrag[p0+3] = packB(vox(r2.y,3.f), vox(r2.z,3.f), vox(r2.w,1.f));
        }
        __syncthreads();

        const int4* __restrict__ bbase = &cfrag[w * 256 + col];
        #pragma unroll
        for (int jp = 0; jp < 4; ++jp) {
            const bf16x8 bfa = __builtin_bit_cast(bf16x8, bbase[jp * 64]);
            const bf16x8 bfb = __builtin_bit_cast(bf16x8, bbase[jp * 64 + 32]);
            const f32x16 dA = __builtin_amdgcn_mfma_f32_32x32x16_bf16(
                afrag, bfa, zero, 0, 0, 0);
            const f32x16 dB = __builtin_amdgcn_mfma_f32_32x32x16_bf16(
                afrag, bfb, zero, 0, 0, 0);
            #pragma unroll
            for (int i = 0; i < 16; ++i)
                rm[i] = min3f(rm[i], dA[i], dB[i]);
        }
    }

    // ---- row-min wrap-up: min over 32 cols (5-level shfl in halves) ----
    const int hi4 = (lane >> 5) * 4;
    #pragma unroll
    for (int i = 0; i < 16; ++i) {
        float v = rm[i];
        v = fminf(v, __shfl_xor(v, 1, 64));
        v = fminf(v, __shfl_xor(v, 2, 64));
        v = fminf(v, __shfl_xor(v, 4, 64));
        v = fminf(v, __shfl_xor(v, 8, 64));
        v = fminf(v, __shfl_xor(v, 16, 64));
        const int r = (i & 3) + 8 * (i >> 2) + hi4;   // C/D map (m74/m101)
        if (col == 0) waveRow[w][r] = v + qxx[r];
    }
    __syncthreads();

    if (w == 0) {                       // lane r (<32) owns query row r
        float s = 0.0f;
        if (lane < QPB) {
            s = fminf(fminf(waveRow[0][lane], waveRow[1][lane]),
                      fminf(waveRow[2][lane], waveRow[3][lane]));
        }
        #pragma unroll
        for (int o = 32; o >= 1; o >>= 1) s += __shfl_xor(s, o, 64);
        if (lane == 0) partials[bid] = s;   // exact int sum of 32 row-mins
    }
}

// ---------------- k2: tiny fixed-order final reduce ----------------
__global__ __launch_bounds__(BLK) void chamfer_finish_kernel(
    const float* __restrict__ partials, float* __restrict__ out)
{
    __shared__ float s1[BLK];
    const int t = threadIdx.x;
    s1[t] = (partials[t] + partials[t + 256])
          + (partials[t + 512] + partials[t + 768]);   // fixed order
    __syncthreads();
    for (int k = 128; k > 0; k >>= 1) {
        if (t < k) s1[t] += s1[t + k];
        __syncthreads();
    }
    if (t == 0) out[0] = s1[0] * SCALE;    // overwrite: no init needed
}

extern "C" void kernel_launch(void* const* d_in, const int* in_sizes, int n_in,
                              void* d_out, int out_size, void* d_ws, size_t ws_size,
                              hipStream_t stream)
{
    const float* preds = (const float*)d_in[0];
    const float* gts   = (const float*)d_in[1];
    float* out = (float*)d_out;
    float* partials = (float*)d_ws;        // 1024 floats

    chamfer_rows_kernel<<<NBLOCKS, BLK, 0, stream>>>(preds, gts, partials);
    chamfer_finish_kernel<<<1, BLK, 0, stream>>>(partials, out);
}

// Round 16
// 19.273 us; speedup vs baseline: 1.3004x; 1.1175x over previous
//
#include <hip/hip_runtime.h>
#include <math.h>

// Voxelized chamfer via bf16 MFMA (32x32x16), occupancy-optimized + fast vox:
//   vox coords are integer-valued fp32, |v| <= ~160 -> EXACT in bf16.
//   A row i : {-2qx, -2qy, -2qz, 1, 1, 0...}   (-2q = exponent shift, exact)
//   B col j : { cx,   cy,   cz, yh, yl, 0...}  (yy = yh+yl exact bf16 split)
//   MFMA   -> yy_j - 2 q_i.c_j  directly; 16-term fp32 accum of exact ints
//   < 2^20 -> exact. row-min + xx_i = chamfer row-min; 1 min3 / 2 evals.
//   loss = mean(row-mins, pred->gt) + mean(row-mins, gt->pred).
//
// R16 change (staging-VALU cut): vox uses (c+off)*20.0f instead of the IEEE
// divide /0.05f. 1/0.05f_stored = 19.999999702: product differs from the
// exactly-rounded quotient by <=~1.5e-8 relative, so truncf flips only when
// both straddle an integer — P ~ 2.4e-6/coord, expected ~0.12 flips/call
// over 49k coords; one flip perturbs the mean by <= ~0.05 << 0.58 threshold.
// Saves ~530 staging instrs/thread (48 div-sequences -> 48 fma), the
// dominant k1 term after R15's occupancy fix.
//
// k1: 1024 blocks = (dir, batch, 32-query tile), 4 blocks/CU resident
//     (16 KB chunked LDS staging; launch_bounds(256,4)). Per chunk: pack
//     1024 candidates as 16B B-frags in LDS, barrier, each of 4 waves scans
//     8 col-tiles of 32 in pairs: 2 ds_read_b128 + 2 MFMA_32x32x16 +
//     16 min3. Row-min wrap-up: 5-level shfl min, +xx, cross-wave LDS min,
//     exact int sum -> partials[bid].
// k2: 1 block, fixed-order tree sum of 1024 partials, out[0] = sum * 2^-14.
//
// Exactness (post-vox): all staged values integer & bf16-exact (|v|<=512
// even / <=2^17 with <=9 sig bits); MFMA products <= ~2^17, 5-term fp32
// accum exact; row mins exact ints; partial = sum of 32 ints < 2^24 exact;
// final fixed-order tree of 1024 exact ints; SCALE = 2^-14 exact.

typedef float  f32x16 __attribute__((ext_vector_type(16)));
typedef short  bf16x8 __attribute__((ext_vector_type(8)));

constexpr int NPTS   = 4096;
constexpr int BLK    = 256;
constexpr int QPB    = 32;             // query rows per block (one 32-tile)
constexpr int NTB    = NPTS / QPB;     // 128 row tiles per (dir, batch)
constexpr int BATCH  = 4;
constexpr int NBLOCKS = 2 * BATCH * NTB;   // 1024
constexpr int CHUNK  = 1024;           // candidates staged per chunk
constexpr float FINF  = 3.402823466e38f;
constexpr float SCALE = 1.0f / 16384.0f;   // 1/(B*N) = 2^-14, exact

__device__ __forceinline__ float vox(float c, float off) {
    return truncf((c + off) * 20.0f);  // fast: see header for flip analysis
}
__device__ __forceinline__ unsigned bfbits(float v) {
    return __float_as_uint(v) >> 16;   // exact for the value classes used
}
__device__ __forceinline__ float min3f(float a, float b, float c) {
    return fminf(fminf(a, b), c);      // clang fuses to v_min3_f32
}
__device__ __forceinline__ int4 packB(float x, float y, float z) {
    const float yy = fmaf(z, z, fmaf(y, y, x * x));      // exact int
    const float hi = floorf(yy * 0.00390625f) * 256.0f;  // exact
    const float lo = yy - hi;                            // in [0,256)
    return make_int4(
        (int)((bfbits(y) << 16) | bfbits(x)),            // k0:cx k1:cy
        (int)((bfbits(hi) << 16) | bfbits(z)),           // k2:cz k3:yh
        (int)(bfbits(lo)),                               // k4:yl k5:0
        0);
}

__global__ __launch_bounds__(BLK, 4) void chamfer_rows_kernel(
    const float* __restrict__ preds,
    const float* __restrict__ gts,
    float* __restrict__ partials)      // [1024]
{
    __shared__ int4  cfrag[CHUNK];     // candidate B-frags (16 KB)
    __shared__ int4  qfrag[QPB];       // query A-frags (prescaled -2, ones)
    __shared__ float qxx[QPB];         // query squared norms (exact ints)
    __shared__ float waveRow[4][QPB];

    const int t    = threadIdx.x;
    const int bid  = blockIdx.x;        // dir*512 + b*128 + tile
    const int dir  = bid >> 9;
    const int rem  = bid & 511;
    const int b    = rem >> 7;
    const int tile = rem & 127;
    const int w    = t >> 6;
    const int lane = t & 63;
    const int col  = lane & 31;         // A row / B col within 32-tile
    const bool lo_g = (lane < 32);      // k=0..7 carrier half

    const float* __restrict__ xb = (dir ? gts : preds) + (size_t)b * NPTS * 3;
    const float* __restrict__ yb = (dir ? preds : gts) + (size_t)b * NPTS * 3;

    constexpr unsigned ONE = 0x3F80u;   // bf16 1.0

    // ---- stage this block's 32 query rows as A-frags ----
    if (t < QPB) {
        const int qi = tile * QPB + t;
        const float x = vox(xb[qi*3+0], 3.0f);
        const float y = vox(xb[qi*3+1], 3.0f);
        const float z = vox(xb[qi*3+2], 1.0f);
        qxx[t] = fmaf(z, z, fmaf(y, y, x * x));
        const float mx = -2.0f * x, my = -2.0f * y, mz = -2.0f * z; // exact
        qfrag[t] = make_int4(
            (int)((bfbits(my) << 16) | bfbits(mx)),          // k0 k1
            (int)((ONE << 16) | bfbits(mz)),                 // k2 k3:1
            (int)(ONE),                                      // k4:1 k5:0
            0);
    }
    __syncthreads();

    // A fragment (lanes>=32 zeroed -> B's k8..15 contribute exactly 0).
    bf16x8 afrag;
    {
        const int4 qv = qfrag[col];
        int4 ai = { lo_g ? qv.x : 0, lo_g ? qv.y : 0, lo_g ? qv.z : 0, 0 };
        afrag = __builtin_bit_cast(bf16x8, ai);
    }

    f32x16 rm;
    #pragma unroll
    for (int i = 0; i < 16; ++i) rm[i] = FINF;
    const f32x16 zero = {};

    const float4* __restrict__ yb4 = (const float4*)yb;

    // ---- 4 chunks: pack 1024 candidates, barrier, scan ----
    #pragma unroll 1
    for (int cc = 0; cc < 4; ++cc) {
        if (cc) __syncthreads();           // previous chunk's readers done
        {
            const int p0 = t * 4;
            const int fi = cc * 768 + t * 3;
            const float4 r0 = yb4[fi + 0];
            const float4 r1 = yb4[fi + 1];
            const float4 r2 = yb4[fi + 2];
            cfrag[p0+0] = packB(vox(r0.x,3.f), vox(r0.y,3.f), vox(r0.z,1.f));
            cfrag[p0+1] = packB(vox(r0.w,3.f), vox(r1.x,3.f), vox(r1.y,1.f));
            cfrag[p0+2] = packB(vox(r1.z,3.f), vox(r1.w,3.f), vox(r2.x,1.f));
            cfrag[p0+3] = packB(vox(r2.y,3.f), vox(r2.z,3.f), vox(r2.w,1.f));
        }
        __syncthreads();

        const int4* __restrict__ bbase = &cfrag[w * 256 + col];
        #pragma unroll
        for (int jp = 0; jp < 4; ++jp) {
            const bf16x8 bfa = __builtin_bit_cast(bf16x8, bbase[jp * 64]);
            const bf16x8 bfb = __builtin_bit_cast(bf16x8, bbase[jp * 64 + 32]);
            const f32x16 dA = __builtin_amdgcn_mfma_f32_32x32x16_bf16(
                afrag, bfa, zero, 0, 0, 0);
            const f32x16 dB = __builtin_amdgcn_mfma_f32_32x32x16_bf16(
                afrag, bfb, zero, 0, 0, 0);
            #pragma unroll
            for (int i = 0; i < 16; ++i)
                rm[i] = min3f(rm[i], dA[i], dB[i]);
        }
    }

    // ---- row-min wrap-up: min over 32 cols (5-level shfl in halves) ----
    const int hi4 = (lane >> 5) * 4;
    #pragma unroll
    for (int i = 0; i < 16; ++i) {
        float v = rm[i];
        v = fminf(v, __shfl_xor(v, 1, 64));
        v = fminf(v, __shfl_xor(v, 2, 64));
        v = fminf(v, __shfl_xor(v, 4, 64));
        v = fminf(v, __shfl_xor(v, 8, 64));
        v = fminf(v, __shfl_xor(v, 16, 64));
        const int r = (i & 3) + 8 * (i >> 2) + hi4;   // C/D map (m74/m101)
        if (col == 0) waveRow[w][r] = v + qxx[r];
    }
    __syncthreads();

    if (w == 0) {                       // lane r (<32) owns query row r
        float s = 0.0f;
        if (lane < QPB) {
            s = fminf(fminf(waveRow[0][lane], waveRow[1][lane]),
                      fminf(waveRow[2][lane], waveRow[3][lane]));
        }
        #pragma unroll
        for (int o = 32; o >= 1; o >>= 1) s += __shfl_xor(s, o, 64);
        if (lane == 0) partials[bid] = s;   // exact int sum of 32 row-mins
    }
}

// ---------------- k2: tiny fixed-order final reduce ----------------
__global__ __launch_bounds__(BLK) void chamfer_finish_kernel(
    const float* __restrict__ partials, float* __restrict__ out)
{
    __shared__ float s1[BLK];
    const int t = threadIdx.x;
    s1[t] = (partials[t] + partials[t + 256])
          + (partials[t + 512] + partials[t + 768]);   // fixed order
    __syncthreads();
    for (int k = 128; k > 0; k >>= 1) {
        if (t < k) s1[t] += s1[t + k];
        __syncthreads();
    }
    if (t == 0) out[0] = s1[0] * SCALE;    // overwrite: no init needed
}

extern "C" void kernel_launch(void* const* d_in, const int* in_sizes, int n_in,
                              void* d_out, int out_size, void* d_ws, size_t ws_size,
                              hipStream_t stream)
{
    const float* preds = (const float*)d_in[0];
    const float* gts   = (const float*)d_in[1];
    float* out = (float*)d_out;
    float* partials = (float*)d_ws;        // 1024 floats

    chamfer_rows_kernel<<<NBLOCKS, BLK, 0, stream>>>(preds, gts, partials);
    chamfer_finish_kernel<<<1, BLK, 0, stream>>>(partials, out);
}

// Round 17
// 17.506 us; speedup vs baseline: 1.4317x; 1.1010x over previous
//
#include <hip/hip_runtime.h>
#include <math.h>

// Voxelized chamfer via bf16 MFMA (32x32x16): 512x512-thread blocks.
//   vox coords are integer-valued fp32, |v| <= ~160 -> EXACT in bf16.
//   A row i : {-2qx, -2qy, -2qz, 1, 1, 0...}   (-2q = exponent shift, exact)
//   B col j : { cx,   cy,   cz, yh, yl, 0...}  (yy = yh+yl exact bf16 split)
//   MFMA   -> yy_j - 2 q_i.c_j  directly; 16-term fp32 accum of exact ints
//   < 2^20 -> exact. row-min + xx_i = chamfer row-min; 1 min3 / 2 evals.
//   loss = mean(row-mins, pred->gt) + mean(row-mins, gt->pred).
//
// R17 changes vs R16 (19.3 us):
//   1. BLK=512, QPB=64, 512 blocks: same 16 waves/CU occupancy (2 blocks x
//      8 waves), same per-thread MFMA scan (waves 0-3 -> query tile A,
//      waves 4-7 -> tile B over the SAME staged chunk), but candidate
//      staging redundancy HALVES: 8 packB/thread (was 16).
//   2. v_cvt_pk_bf16_f32 packs each bf16 pair in 1 instr (vs shift/or).
//      Bit-identical: all packed values exactly representable -> RNE = id.
//   vox keeps R16's (c+off)*20.0f fast path (flip analysis in R16 header).
//
// k1: 512 blocks = (dir, batch, 64-query tile). Per chunk (4 x 1024 cands,
//     16 KB LDS): 512 threads pack 2 points each via 3 float2 loads,
//     barrier, each wave scans 256 candidates for its tile: 4x{2
//     ds_read_b128 + 2 MFMA_32x32x16 + 16 min3}. Wrap-up: 5-level shfl min,
//     +xx, cross-wave LDS min per tile-group -> partials[2*bid+g].
// k2: 1 block, fixed-order tree sum of 1024 partials, out[0] = sum * 2^-14.
//
// Exactness: staged values integer & bf16-exact (|v|<=512 even / <=2^17
// with <=9 sig bits); MFMA products <= ~2^17, 5-term fp32 accum exact; row
// mins exact ints; partial = sum of 32 ints < 2^24 exact; final fixed-order
// tree of 1024 exact ints; SCALE = 2^-14 exact.

typedef float  f32x16 __attribute__((ext_vector_type(16)));
typedef short  bf16x8 __attribute__((ext_vector_type(8)));

constexpr int NPTS   = 4096;
constexpr int BLK    = 512;
constexpr int QPB    = 64;             // query rows per block (two 32-tiles)
constexpr int NTB    = NPTS / QPB;     // 64 row tiles per (dir, batch)
constexpr int BATCH  = 4;
constexpr int NBLOCKS = 2 * BATCH * NTB;   // 512
constexpr int CHUNK  = 1024;           // candidates staged per chunk
constexpr float FINF  = 3.402823466e38f;
constexpr float SCALE = 1.0f / 16384.0f;   // 1/(B*N) = 2^-14, exact

__device__ __forceinline__ float vox(float c, float off) {
    return truncf((c + off) * 20.0f);  // fast vox (R16 flip analysis)
}
__device__ __forceinline__ unsigned cvtpk(float lo, float hi) {
    unsigned r;                        // low16 = bf16(lo), high16 = bf16(hi)
    asm("v_cvt_pk_bf16_f32 %0, %1, %2" : "=v"(r) : "v"(lo), "v"(hi));
    return r;                          // exact: inputs exactly representable
}
__device__ __forceinline__ float min3f(float a, float b, float c) {
    return fminf(fminf(a, b), c);      // clang fuses to v_min3_f32
}
__device__ __forceinline__ int4 packB(float x, float y, float z) {
    const float yy = fmaf(z, z, fmaf(y, y, x * x));      // exact int
    const float hi = floorf(yy * 0.00390625f) * 256.0f;  // exact
    const float lo = yy - hi;                            // in [0,256)
    return make_int4((int)cvtpk(x, y),                   // k0:cx k1:cy
                     (int)cvtpk(z, hi),                  // k2:cz k3:yh
                     (int)cvtpk(lo, 0.0f),               // k4:yl k5:0
                     0);
}

__global__ __launch_bounds__(BLK, 4) void chamfer_rows_kernel(
    const float* __restrict__ preds,
    const float* __restrict__ gts,
    float* __restrict__ partials)      // [1024]
{
    __shared__ int4  cfrag[CHUNK];     // candidate B-frags (16 KB)
    __shared__ int4  qfrag[QPB];       // query A-frags (prescaled -2, ones)
    __shared__ float qxx[QPB];         // query squared norms (exact ints)
    __shared__ float waveRow[8][32];

    const int t    = threadIdx.x;
    const int bid  = blockIdx.x;        // dir*256 + b*64 + tile
    const int dir  = bid >> 8;
    const int rem  = bid & 255;
    const int b    = rem >> 6;
    const int tile = rem & 63;
    const int w    = t >> 6;            // wave 0..7
    const int g    = w >> 2;            // tile-group 0/1
    const int wsub = w & 3;             // candidate segment within chunk
    const int lane = t & 63;
    const int col  = lane & 31;         // A row / B col within 32-tile
    const bool lo_g = (lane < 32);      // k=0..7 carrier half

    const float* __restrict__ xb = (dir ? gts : preds) + (size_t)b * NPTS * 3;
    const float* __restrict__ yb = (dir ? preds : gts) + (size_t)b * NPTS * 3;

    // ---- stage this block's 64 query rows as A-frags ----
    if (t < QPB) {
        const int qi = tile * QPB + t;
        const float x = vox(xb[qi*3+0], 3.0f);
        const float y = vox(xb[qi*3+1], 3.0f);
        const float z = vox(xb[qi*3+2], 1.0f);
        qxx[t] = fmaf(z, z, fmaf(y, y, x * x));
        const float mx = -2.0f * x, my = -2.0f * y, mz = -2.0f * z; // exact
        qfrag[t] = make_int4((int)cvtpk(mx, my),         // k0 k1
                             (int)cvtpk(mz, 1.0f),       // k2 k3:1
                             (int)cvtpk(1.0f, 0.0f),     // k4:1 k5:0
                             0);
    }
    __syncthreads();

    // A fragment for this wave's 32-query tile (lanes>=32 zeroed -> B's
    // k8..15 contribute exactly 0).
    bf16x8 afrag;
    {
        const int4 qv = qfrag[g * 32 + col];
        int4 ai = { lo_g ? qv.x : 0, lo_g ? qv.y : 0, lo_g ? qv.z : 0, 0 };
        afrag = __builtin_bit_cast(bf16x8, ai);
    }

    f32x16 rm;
    #pragma unroll
    for (int i = 0; i < 16; ++i) rm[i] = FINF;
    const f32x16 zero = {};

    const float2* __restrict__ yb2 = (const float2*)yb;

    // ---- 4 chunks: pack 1024 candidates (2/thread), barrier, scan ----
    #pragma unroll 1
    for (int cc = 0; cc < 4; ++cc) {
        if (cc) __syncthreads();           // previous chunk's readers done
        {
            const int p0 = t * 2;
            const int fi = cc * 1536 + t * 3;
            const float2 r0 = yb2[fi + 0];
            const float2 r1 = yb2[fi + 1];
            const float2 r2 = yb2[fi + 2];
            cfrag[p0+0] = packB(vox(r0.x,3.f), vox(r0.y,3.f), vox(r1.x,1.f));
            cfrag[p0+1] = packB(vox(r1.y,3.f), vox(r2.x,3.f), vox(r2.y,1.f));
        }
        __syncthreads();

        const int4* __restrict__ bbase = &cfrag[wsub * 256 + col];
        #pragma unroll
        for (int jp = 0; jp < 4; ++jp) {
            const bf16x8 bfa = __builtin_bit_cast(bf16x8, bbase[jp * 64]);
            const bf16x8 bfb = __builtin_bit_cast(bf16x8, bbase[jp * 64 + 32]);
            const f32x16 dA = __builtin_amdgcn_mfma_f32_32x32x16_bf16(
                afrag, bfa, zero, 0, 0, 0);
            const f32x16 dB = __builtin_amdgcn_mfma_f32_32x32x16_bf16(
                afrag, bfb, zero, 0, 0, 0);
            #pragma unroll
            for (int i = 0; i < 16; ++i)
                rm[i] = min3f(rm[i], dA[i], dB[i]);
        }
    }

    // ---- row-min wrap-up: min over 32 cols (5-level shfl in halves) ----
    const int hi4 = (lane >> 5) * 4;
    #pragma unroll
    for (int i = 0; i < 16; ++i) {
        float v = rm[i];
        v = fminf(v, __shfl_xor(v, 1, 64));
        v = fminf(v, __shfl_xor(v, 2, 64));
        v = fminf(v, __shfl_xor(v, 4, 64));
        v = fminf(v, __shfl_xor(v, 8, 64));
        v = fminf(v, __shfl_xor(v, 16, 64));
        const int r = (i & 3) + 8 * (i >> 2) + hi4;   // C/D map (m74/m101)
        if (col == 0) waveRow[w][r] = v + qxx[g * 32 + r];
    }
    __syncthreads();

    // ---- per-tile-group combine: wave 0 -> tile A, wave 4 -> tile B ----
    if ((w & 3) == 0) {                 // waves 0 and 4
        float s = 0.0f;
        if (lane < 32) {
            s = fminf(fminf(waveRow[w + 0][lane], waveRow[w + 1][lane]),
                      fminf(waveRow[w + 2][lane], waveRow[w + 3][lane]));
        }
        #pragma unroll
        for (int o = 32; o >= 1; o >>= 1) s += __shfl_xor(s, o, 64);
        if (lane == 0) partials[bid * 2 + g] = s;   // exact int sum of 32
    }
}

// ---------------- k2: tiny fixed-order final reduce ----------------
__global__ __launch_bounds__(256) void chamfer_finish_kernel(
    const float* __restrict__ partials, float* __restrict__ out)
{
    __shared__ float s1[256];
    const int t = threadIdx.x;
    s1[t] = (partials[t] + partials[t + 256])
          + (partials[t + 512] + partials[t + 768]);   // fixed order
    __syncthreads();
    for (int k = 128; k > 0; k >>= 1) {
        if (t < k) s1[t] += s1[t + k];
        __syncthreads();
    }
    if (t == 0) out[0] = s1[0] * SCALE;    // overwrite: no init needed
}

extern "C" void kernel_launch(void* const* d_in, const int* in_sizes, int n_in,
                              void* d_out, int out_size, void* d_ws, size_t ws_size,
                              hipStream_t stream)
{
    const float* preds = (const float*)d_in[0];
    const float* gts   = (const float*)d_in[1];
    float* out = (float*)d_out;
    float* partials = (float*)d_ws;        // 1024 floats

    chamfer_rows_kernel<<<NBLOCKS, BLK, 0, stream>>>(preds, gts, partials);
    chamfer_finish_kernel<<<1, 256, 0, stream>>>(partials, out);
}

// Round 18
// 16.757 us; speedup vs baseline: 1.4957x; 1.0447x over previous
//
#include <hip/hip_runtime.h>
#include <math.h>

// Voxelized chamfer via bf16 MFMA (32x32x16): 256 x 1024-thread blocks.
//   vox coords are integer-valued fp32, |v| <= ~160 -> EXACT in bf16.
//   A row i : {-2qx, -2qy, -2qz, 1, 1, 0...}   (-2q = exponent shift, exact)
//   B col j : { cx,   cy,   cz, yh, yl, 0...}  (yy = yh+yl exact bf16 split)
//   MFMA   -> yy_j - 2 q_i.c_j  directly; 16-term fp32 accum of exact ints
//   < 2^20 -> exact. row-min + xx_i = chamfer row-min; 1 min3 / 2 evals.
//   loss = mean(row-mins, pred->gt) + mean(row-mins, gt->pred).
//
// R18 changes vs R17 (17.5 us):
//   1. BLK=1024, QPB=128, 256 blocks: same 16 waves/CU (1 block/CU,
//      launch_bounds(1024,4)), but candidate-staging redundancy HALVES
//      again: 4 packB/thread (was 8). Waves split 4 tile-groups x 4
//      candidate-segments over the shared chunk.
//   2. CHUNK=2048 (32 KB LDS): 2 chunks instead of 4 -> barriers 9 -> 5.
//   Accepted risk: 1 block/CU loses cross-block barrier overlap.
//   vox keeps (c+off)*20.0f (R16 flip analysis); cvtpk packs (R17).
//
// k1: 256 blocks = (dir, batch, 128-query tile). Per chunk (2 x 2048
//     cands): 1024 threads pack 2 points each via 3 float2 loads, barrier,
//     each wave scans its 512-cand segment for its 32-query tile:
//     8 x {2 ds_read_b128 + 2 MFMA_32x32x16 + 16 min3}. Wrap-up: 5-level
//     shfl min, +xx, cross-wave LDS min per tile-group ->
//     partials[4*bid+g].
// k2: 1 block, fixed-order tree sum of 1024 partials, out[0] = sum * 2^-14
//     (byte-identical to R17's verified k2).
//
// Exactness: staged values integer & bf16-exact (|v|<=512 even / <=2^17
// with <=9 sig bits); MFMA products <= ~2^17, 5-term fp32 accum exact; row
// mins exact ints; partial = sum of 32 ints < 2^24 exact; final fixed-order
// tree of 1024 exact ints; SCALE = 2^-14 exact.

typedef float  f32x16 __attribute__((ext_vector_type(16)));
typedef short  bf16x8 __attribute__((ext_vector_type(8)));

constexpr int NPTS   = 4096;
constexpr int BLK    = 1024;
constexpr int QPB    = 128;            // query rows per block (4 x 32-tiles)
constexpr int NTB    = NPTS / QPB;     // 32 row tiles per (dir, batch)
constexpr int BATCH  = 4;
constexpr int NBLOCKS = 2 * BATCH * NTB;   // 256
constexpr int CHUNK  = 2048;           // candidates staged per chunk
constexpr float FINF  = 3.402823466e38f;
constexpr float SCALE = 1.0f / 16384.0f;   // 1/(B*N) = 2^-14, exact

__device__ __forceinline__ float vox(float c, float off) {
    return truncf((c + off) * 20.0f);  // fast vox (R16 flip analysis)
}
__device__ __forceinline__ unsigned cvtpk(float lo, float hi) {
    unsigned r;                        // low16 = bf16(lo), high16 = bf16(hi)
    asm("v_cvt_pk_bf16_f32 %0, %1, %2" : "=v"(r) : "v"(lo), "v"(hi));
    return r;                          // exact: inputs exactly representable
}
__device__ __forceinline__ float min3f(float a, float b, float c) {
    return fminf(fminf(a, b), c);      // clang fuses to v_min3_f32
}
__device__ __forceinline__ int4 packB(float x, float y, float z) {
    const float yy = fmaf(z, z, fmaf(y, y, x * x));      // exact int
    const float hi = floorf(yy * 0.00390625f) * 256.0f;  // exact
    const float lo = yy - hi;                            // in [0,256)
    return make_int4((int)cvtpk(x, y),                   // k0:cx k1:cy
                     (int)cvtpk(z, hi),                  // k2:cz k3:yh
                     (int)cvtpk(lo, 0.0f),               // k4:yl k5:0
                     0);
}

__global__ __launch_bounds__(BLK, 4) void chamfer_rows_kernel(
    const float* __restrict__ preds,
    const float* __restrict__ gts,
    float* __restrict__ partials)      // [1024]
{
    __shared__ int4  cfrag[CHUNK];     // candidate B-frags (32 KB)
    __shared__ int4  qfrag[QPB];       // query A-frags (prescaled -2, ones)
    __shared__ float qxx[QPB];         // query squared norms (exact ints)
    __shared__ float waveRow[16][32];

    const int t    = threadIdx.x;
    const int bid  = blockIdx.x;        // dir*128 + b*32 + tile
    const int dir  = bid >> 7;
    const int rem  = bid & 127;
    const int b    = rem >> 5;
    const int tile = rem & 31;
    const int w    = t >> 6;            // wave 0..15
    const int g    = w >> 2;            // tile-group 0..3
    const int wsub = w & 3;             // candidate segment within chunk
    const int lane = t & 63;
    const int col  = lane & 31;         // A row / B col within 32-tile
    const bool lo_g = (lane < 32);      // k=0..7 carrier half

    const float* __restrict__ xb = (dir ? gts : preds) + (size_t)b * NPTS * 3;
    const float* __restrict__ yb = (dir ? preds : gts) + (size_t)b * NPTS * 3;

    // ---- stage this block's 128 query rows as A-frags ----
    if (t < QPB) {
        const int qi = tile * QPB + t;
        const float x = vox(xb[qi*3+0], 3.0f);
        const float y = vox(xb[qi*3+1], 3.0f);
        const float z = vox(xb[qi*3+2], 1.0f);
        qxx[t] = fmaf(z, z, fmaf(y, y, x * x));
        const float mx = -2.0f * x, my = -2.0f * y, mz = -2.0f * z; // exact
        qfrag[t] = make_int4((int)cvtpk(mx, my),         // k0 k1
                             (int)cvtpk(mz, 1.0f),       // k2 k3:1
                             (int)cvtpk(1.0f, 0.0f),     // k4:1 k5:0
                             0);
    }
    __syncthreads();

    // A fragment for this wave's 32-query tile (lanes>=32 zeroed -> B's
    // k8..15 contribute exactly 0).
    bf16x8 afrag;
    {
        const int4 qv = qfrag[g * 32 + col];
        int4 ai = { lo_g ? qv.x : 0, lo_g ? qv.y : 0, lo_g ? qv.z : 0, 0 };
        afrag = __builtin_bit_cast(bf16x8, ai);
    }

    f32x16 rm;
    #pragma unroll
    for (int i = 0; i < 16; ++i) rm[i] = FINF;
    const f32x16 zero = {};

    const float2* __restrict__ yb2 = (const float2*)yb;

    // ---- 2 chunks: pack 2048 candidates (2/thread), barrier, scan ----
    #pragma unroll 1
    for (int cc = 0; cc < 2; ++cc) {
        if (cc) __syncthreads();           // previous chunk's readers done
        {
            const int p0 = t * 2;
            const int fi = cc * 3072 + t * 3;
            const float2 r0 = yb2[fi + 0];
            const float2 r1 = yb2[fi + 1];
            const float2 r2 = yb2[fi + 2];
            cfrag[p0+0] = packB(vox(r0.x,3.f), vox(r0.y,3.f), vox(r1.x,1.f));
            cfrag[p0+1] = packB(vox(r1.y,3.f), vox(r2.x,3.f), vox(r2.y,1.f));
        }
        __syncthreads();

        const int4* __restrict__ bbase = &cfrag[wsub * 512 + col];
        #pragma unroll
        for (int jp = 0; jp < 8; ++jp) {
            const bf16x8 bfa = __builtin_bit_cast(bf16x8, bbase[jp * 64]);
            const bf16x8 bfb = __builtin_bit_cast(bf16x8, bbase[jp * 64 + 32]);
            const f32x16 dA = __builtin_amdgcn_mfma_f32_32x32x16_bf16(
                afrag, bfa, zero, 0, 0, 0);
            const f32x16 dB = __builtin_amdgcn_mfma_f32_32x32x16_bf16(
                afrag, bfb, zero, 0, 0, 0);
            #pragma unroll
            for (int i = 0; i < 16; ++i)
                rm[i] = min3f(rm[i], dA[i], dB[i]);
        }
    }

    // ---- row-min wrap-up: min over 32 cols (5-level shfl in halves) ----
    const int hi4 = (lane >> 5) * 4;
    #pragma unroll
    for (int i = 0; i < 16; ++i) {
        float v = rm[i];
        v = fminf(v, __shfl_xor(v, 1, 64));
        v = fminf(v, __shfl_xor(v, 2, 64));
        v = fminf(v, __shfl_xor(v, 4, 64));
        v = fminf(v, __shfl_xor(v, 8, 64));
        v = fminf(v, __shfl_xor(v, 16, 64));
        const int r = (i & 3) + 8 * (i >> 2) + hi4;   // C/D map (m74/m101)
        if (col == 0) waveRow[w][r] = v + qxx[g * 32 + r];
    }
    __syncthreads();

    // ---- per-tile-group combine: waves 0/4/8/12 ----
    if ((w & 3) == 0) {
        float s = 0.0f;
        if (lane < 32) {
            s = fminf(fminf(waveRow[w + 0][lane], waveRow[w + 1][lane]),
                      fminf(waveRow[w + 2][lane], waveRow[w + 3][lane]));
        }
        #pragma unroll
        for (int o = 32; o >= 1; o >>= 1) s += __shfl_xor(s, o, 64);
        if (lane == 0) partials[bid * 4 + g] = s;   // exact int sum of 32
    }
}

// ---------------- k2: tiny fixed-order final reduce ----------------
__global__ __launch_bounds__(256) void chamfer_finish_kernel(
    const float* __restrict__ partials, float* __restrict__ out)
{
    __shared__ float s1[256];
    const int t = threadIdx.x;
    s1[t] = (partials[t] + partials[t + 256])
          + (partials[t + 512] + partials[t + 768]);   // fixed order
    __syncthreads();
    for (int k = 128; k > 0; k >>= 1) {
        if (t < k) s1[t] += s1[t + k];
        __syncthreads();
    }
    if (t == 0) out[0] = s1[0] * SCALE;    // overwrite: no init needed
}

extern "C" void kernel_launch(void* const* d_in, const int* in_sizes, int n_in,
                              void* d_out, int out_size, void* d_ws, size_t ws_size,
                              hipStream_t stream)
{
    const float* preds = (const float*)d_in[0];
    const float* gts   = (const float*)d_in[1];
    float* out = (float*)d_out;
    float* partials = (float*)d_ws;        // 1024 floats

    chamfer_rows_kernel<<<NBLOCKS, BLK, 0, stream>>>(preds, gts, partials);
    chamfer_finish_kernel<<<1, 256, 0, stream>>>(partials, out);
}